// Round 1
// baseline (230.060 us; speedup 1.0000x reference)
//
#include <hip/hip_runtime.h>
#include <cstdint>
#include <cstddef>

// ---------------------------------------------------------------------------
// ChannelWiseCrossAttention: B=4, C=64, H=W=64, N=4096
// q = x1*Wq+bq ; k = x2*Wk+bk ; v = x2*Wv+bv (1x1 convs)
// attn = softmax_j(q^T k) ; out = gamma * (v @ attn^T) + x1
// Implemented as: 3 conv kernels -> bf16 q[b][i][c], k[b][j][c], v[b][c][j]
// then flash-attention with mfma_f32_16x16x32_bf16.
// ---------------------------------------------------------------------------

typedef __bf16 bf16x8 __attribute__((ext_vector_type(8)));
typedef float f32x4 __attribute__((ext_vector_type(4)));

#define LOG2E 1.44269504088896340736f

constexpr int C = 64;
constexpr int N = 4096;   // 64*64
constexpr int B = 4;

// ---------------------------------------------------------------------------
// 1x1 conv: out[b, o, n] = sum_c x[b, c, n] * w[o, c] + bias[o]
// TRANSPOSE_OUT=true  -> store out_t[b][n][o]  (bf16)   (for q, k)
// TRANSPOSE_OUT=false -> store out  [b][o][n]  (bf16)   (for v)
// grid = B * (N/64), block = 256.  Each block: one batch, 64 pixels, all 64 o.
// ---------------------------------------------------------------------------
template <bool TRANSPOSE_OUT>
__global__ __launch_bounds__(256) void conv1x1_kernel(
    const float* __restrict__ x, const float* __restrict__ w,
    const float* __restrict__ bias, __bf16* __restrict__ out)
{
    __shared__ float w_lds[64][65];   // pad 65: conflict-free per-c reads
    __shared__ float x_lds[64][68];   // pad 68: 16B-aligned rows, ok transpose

    const int tid   = threadIdx.x;
    const int b     = blockIdx.x >> 6;
    const int nbase = (blockIdx.x & 63) * 64;

    // Stage W (64x64) and x-tile (64 c x 64 pixels), coalesced float4 loads.
#pragma unroll
    for (int it = 0; it < 4; ++it) {
        int idx4 = it * 256 + tid;           // 0..1023
        int r = idx4 >> 4;                   // 0..63
        int c4 = (idx4 & 15) * 4;            // 0..60
        float4 wv = *(const float4*)(w + r * 64 + c4);
        w_lds[r][c4 + 0] = wv.x; w_lds[r][c4 + 1] = wv.y;
        w_lds[r][c4 + 2] = wv.z; w_lds[r][c4 + 3] = wv.w;
        float4 xv = *(const float4*)(x + ((size_t)b * C + r) * N + nbase + c4);
        *(float4*)&x_lds[r][c4] = xv;        // 16B aligned (68*4=272 % 16 == 0)
    }
    __syncthreads();

    // thread = (o = tid&63, pixel-group pg = tid>>6 -> 16 pixels)
    const int o  = tid & 63;
    const int pg = tid >> 6;

    float acc[16];
    const float bv = bias[o];
#pragma unroll
    for (int i = 0; i < 16; ++i) acc[i] = bv;

#pragma unroll 4
    for (int c = 0; c < 64; ++c) {
        float wv = w_lds[o][c];              // banks (o + c) % 32 -> 2-way, free
        const float* xr = &x_lds[c][pg * 16]; // wave-uniform address: broadcast
        float4 a0 = *(const float4*)(xr + 0);
        float4 a1 = *(const float4*)(xr + 4);
        float4 a2 = *(const float4*)(xr + 8);
        float4 a3 = *(const float4*)(xr + 12);
        acc[0]  += wv * a0.x; acc[1]  += wv * a0.y; acc[2]  += wv * a0.z; acc[3]  += wv * a0.w;
        acc[4]  += wv * a1.x; acc[5]  += wv * a1.y; acc[6]  += wv * a1.z; acc[7]  += wv * a1.w;
        acc[8]  += wv * a2.x; acc[9]  += wv * a2.y; acc[10] += wv * a2.z; acc[11] += wv * a2.w;
        acc[12] += wv * a3.x; acc[13] += wv * a3.y; acc[14] += wv * a3.z; acc[15] += wv * a3.w;
    }

    if (TRANSPOSE_OUT) {
        // Transpose through LDS (reuse x_lds as [o][p]) for coalesced stores.
        __syncthreads();
#pragma unroll
        for (int i = 0; i < 16; ++i) x_lds[o][pg * 16 + i] = acc[i];
        __syncthreads();
        const int p = tid & 63;              // pixel
        const int g = tid >> 6;              // o-group of 16
        bf16x8 v0, v1;
#pragma unroll
        for (int i = 0; i < 8; ++i) v0[i] = (__bf16)x_lds[g * 16 + i][p];
#pragma unroll
        for (int i = 0; i < 8; ++i) v1[i] = (__bf16)x_lds[g * 16 + 8 + i][p];
        __bf16* dst = out + ((size_t)b * N + nbase + p) * C + g * 16;
        *(bf16x8*)(dst + 0) = v0;
        *(bf16x8*)(dst + 8) = v1;
    } else {
        bf16x8 v0, v1;
#pragma unroll
        for (int i = 0; i < 8; ++i) v0[i] = (__bf16)acc[i];
#pragma unroll
        for (int i = 0; i < 8; ++i) v1[i] = (__bf16)acc[8 + i];
        __bf16* dst = out + ((size_t)b * C + o) * N + nbase + pg * 16;
        *(bf16x8*)(dst + 0) = v0;
        *(bf16x8*)(dst + 8) = v1;
    }
}

// ---------------------------------------------------------------------------
// Flash attention (bf16 MFMA 16x16x32).
// grid = B * (N/64) = 256 blocks, 256 threads (4 waves). Each wave: 16 Q-rows.
// S tile per wave: 16 x 64 (4 x 16x16 mfma, 2 k-steps over C=64).
// Online softmax; P -> LDS (C/D layout -> A layout transform); PV accumulate.
// Epilogue: O/l, transpose via LDS, out = gamma*O + x1 (coalesced).
// Layouts (verified per guide m89/m91):
//   A frag:  A[m = lane&15][k = (lane>>4)*8 + j]   (8 bf16, contiguous 16B)
//   B frag:  B[k = (lane>>4)*8 + j][n = lane&15]
//   C/D:     row = (lane>>4)*4 + reg, col = lane&15
// ---------------------------------------------------------------------------
__global__ __launch_bounds__(256) void attn_kernel(
    const __bf16* __restrict__ qg, const __bf16* __restrict__ kg,
    const __bf16* __restrict__ vg, const float* __restrict__ x1,
    const float* __restrict__ gamma, float* __restrict__ out)
{
    __shared__ __bf16 lds_p[4][16][72];   // per-wave P tile, pad 72 (2-way max)
    __shared__ float  lds_o[4][16][65];   // per-wave O transpose, pad 65

    const int tid  = threadIdx.x;
    const int wave = tid >> 6;
    const int lane = tid & 63;
    const int l    = lane & 15;
    const int qd   = lane >> 4;

    const int b     = blockIdx.x >> 6;
    const int ibase = (blockIdx.x & 63) * 64 + wave * 16;   // this wave's rows

    const __bf16* qb = qg + (size_t)b * N * C;   // [i][c]
    const __bf16* kb = kg + (size_t)b * N * C;   // [j][c]
    const __bf16* vb = vg + (size_t)b * C * N;   // [c][j]

    // Q fragments: reused across all j-tiles. A[m=l][k = ks*32 + qd*8 + jj]
    bf16x8 aq0 = *(const bf16x8*)(qb + (size_t)(ibase + l) * C + qd * 8);
    bf16x8 aq1 = *(const bf16x8*)(qb + (size_t)(ibase + l) * C + 32 + qd * 8);

    f32x4 accO[4];
#pragma unroll
    for (int ct = 0; ct < 4; ++ct) accO[ct] = (f32x4){0.f, 0.f, 0.f, 0.f};
    float m_i[4], l_i[4];
#pragma unroll
    for (int r = 0; r < 4; ++r) { m_i[r] = -__builtin_inff(); l_i[r] = 0.f; }

    for (int jt64 = 0; jt64 < 64; ++jt64) {
        const int jbase = jt64 * 64;

        // --- load K^T and V B-fragments for this tile (contiguous 16B each)
        bf16x8 bk[4][2];   // [j-subtile][k-step]: B[k=c][n=j] = K[j][c]
        bf16x8 bvf[4][2];  // [c-subtile][k-step]: B[k=j][n=c] = Vt[c][j]
#pragma unroll
        for (int jt = 0; jt < 4; ++jt)
#pragma unroll
            for (int ks = 0; ks < 2; ++ks)
                bk[jt][ks] = *(const bf16x8*)(kb + (size_t)(jbase + jt * 16 + l) * C + ks * 32 + qd * 8);
#pragma unroll
        for (int ct = 0; ct < 4; ++ct)
#pragma unroll
            for (int ks = 0; ks < 2; ++ks)
                bvf[ct][ks] = *(const bf16x8*)(vb + (size_t)(ct * 16 + l) * N + jbase + ks * 32 + qd * 8);

        // --- S = Q K^T  (rows qd*4+r, cols jt*16+l)
        f32x4 accS[4];
#pragma unroll
        for (int jt = 0; jt < 4; ++jt) {
            accS[jt] = (f32x4){0.f, 0.f, 0.f, 0.f};
            accS[jt] = __builtin_amdgcn_mfma_f32_16x16x32_bf16(aq0, bk[jt][0], accS[jt], 0, 0, 0);
            accS[jt] = __builtin_amdgcn_mfma_f32_16x16x32_bf16(aq1, bk[jt][1], accS[jt], 0, 0, 0);
        }

        // --- online softmax over this tile's 64 columns
        float mnew[4], alpha[4], psum[4];
#pragma unroll
        for (int r = 0; r < 4; ++r) {
            float t = fmaxf(fmaxf(accS[0][r], accS[1][r]), fmaxf(accS[2][r], accS[3][r]));
            t = fmaxf(t, __shfl_xor(t, 1));
            t = fmaxf(t, __shfl_xor(t, 2));
            t = fmaxf(t, __shfl_xor(t, 4));
            t = fmaxf(t, __shfl_xor(t, 8));
            mnew[r]  = fmaxf(m_i[r], t);
            alpha[r] = exp2f((m_i[r] - mnew[r]) * LOG2E);
            psum[r]  = 0.f;
        }
#pragma unroll
        for (int jt = 0; jt < 4; ++jt)
#pragma unroll
            for (int r = 0; r < 4; ++r) {
                float p = exp2f((accS[jt][r] - mnew[r]) * LOG2E);
                psum[r] += p;
                lds_p[wave][qd * 4 + r][jt * 16 + l] = (__bf16)p;
            }
#pragma unroll
        for (int r = 0; r < 4; ++r) {
            float s = psum[r];
            s += __shfl_xor(s, 1);
            s += __shfl_xor(s, 2);
            s += __shfl_xor(s, 4);
            s += __shfl_xor(s, 8);
            l_i[r] = l_i[r] * alpha[r] + s;
            m_i[r] = mnew[r];
        }
#pragma unroll
        for (int ct = 0; ct < 4; ++ct)
#pragma unroll
            for (int r = 0; r < 4; ++r) accO[ct][r] *= alpha[r];

        // P is per-wave in LDS; wait for our own ds_writes, then read A-frags.
        asm volatile("s_waitcnt lgkmcnt(0)" ::: "memory");
        bf16x8 ap0 = *(const bf16x8*)&lds_p[wave][l][qd * 8];
        bf16x8 ap1 = *(const bf16x8*)&lds_p[wave][l][32 + qd * 8];

        // --- O += P V   (rows qd*4+r, cols ct*16+l)
#pragma unroll
        for (int ct = 0; ct < 4; ++ct) {
            accO[ct] = __builtin_amdgcn_mfma_f32_16x16x32_bf16(ap0, bvf[ct][0], accO[ct], 0, 0, 0);
            accO[ct] = __builtin_amdgcn_mfma_f32_16x16x32_bf16(ap1, bvf[ct][1], accO[ct], 0, 0, 0);
        }
    }

    // --- epilogue: O/l, transpose through LDS, out = gamma*O + x1
    float inv[4];
#pragma unroll
    for (int r = 0; r < 4; ++r) inv[r] = 1.f / l_i[r];
#pragma unroll
    for (int ct = 0; ct < 4; ++ct)
#pragma unroll
        for (int r = 0; r < 4; ++r)
            lds_o[wave][qd * 4 + r][ct * 16 + l] = accO[ct][r] * inv[r];
    asm volatile("s_waitcnt lgkmcnt(0)" ::: "memory");

    const float g = gamma[0];
#pragma unroll
    for (int t = 0; t < 16; ++t) {
        int c = qd * 16 + t;
        size_t idx = ((size_t)b * C + c) * N + ibase + l;
        out[idx] = g * lds_o[wave][l][c] + x1[idx];
    }
}

// ---------------------------------------------------------------------------
extern "C" void kernel_launch(void* const* d_in, const int* in_sizes, int n_in,
                              void* d_out, int out_size, void* d_ws, size_t ws_size,
                              hipStream_t stream) {
    const float* x1    = (const float*)d_in[0];
    const float* x2    = (const float*)d_in[1];
    const float* wq    = (const float*)d_in[2];
    const float* bq    = (const float*)d_in[3];
    const float* wk    = (const float*)d_in[4];
    const float* bk    = (const float*)d_in[5];
    const float* wv    = (const float*)d_in[6];
    const float* bv    = (const float*)d_in[7];
    const float* gamma = (const float*)d_in[8];
    float* out = (float*)d_out;

    __bf16* qws = (__bf16*)d_ws;                       // [B][N][C] bf16, 2 MB
    __bf16* kws = qws + (size_t)B * N * C;             // [B][N][C] bf16, 2 MB
    __bf16* vws = kws + (size_t)B * N * C;             // [B][C][N] bf16, 2 MB

    const int blocks = B * (N / 64);                   // 256
    conv1x1_kernel<true ><<<blocks, 256, 0, stream>>>(x1, wq, bq, qws);
    conv1x1_kernel<true ><<<blocks, 256, 0, stream>>>(x2, wk, bk, kws);
    conv1x1_kernel<false><<<blocks, 256, 0, stream>>>(x2, wv, bv, vws);
    attn_kernel<<<blocks, 256, 0, stream>>>(qws, kws, vws, x1, gamma, out);
}